// Round 3
// baseline (1371.597 us; speedup 1.0000x reference)
//
#include <hip/hip_runtime.h>

// Sizes fixed by the problem
#define Bb   64
#define Ee   2048
#define Tt   64
#define Gg   4096
#define Ii   256
#define Hh   32
#define Dd   64

using f32x4_t  = __attribute__((ext_vector_type(4))) float;

__device__ __forceinline__ float gelu_f(float x) {
  return 0.5f * x * (1.0f + erff(x * 0.70710678118654752f));
}

// ---------------- state copy fused with KV-cache update at token_index ----------------
__global__ void copy_state_k(const float4* __restrict__ src, float4* __restrict__ dst,
                             const float4* __restrict__ kb, const float4* __restrict__ vb,
                             const int* __restrict__ tokp) {
  const int t = *tokp;
  const long n4 = (long)128 * Ii * (Ee / 4);
  long i = (long)blockIdx.x * blockDim.x + threadIdx.x;
  const long stride = (long)gridDim.x * blockDim.x;
  for (; i < n4; i += stride) {
    long row = i >> 9;                 // / (Ee/4)
    int tt = (int)(row & (Ii - 1));
    float4 v;
    if (tt == t) {                     // wave-uniform (rows are 512 float4 wide)
      int bh  = (int)(row >> 8);       // 0..127
      int col = (int)(i & 511);
      const float4* s = (bh < Bb) ? kb : vb;
      v = s[(long)(bh & (Bb - 1)) * (Ee / 4) + col];
    } else {
      v = src[i];
    }
    dst[i] = v;
  }
}

// ---------------- layer norm, fused split-K reduce + optional chained 2nd LN ----------------
// KB==0: read in1[base]. KB>0: row value = sum_k in1[k*kstr4 + base] (partial arena).
// GELU+KB>0: second operand = sum_k in1[k*kstr4 + off2 + base].
// SECOND: also emit out3 = LN(out1_row, scale=None, bias2) -- stats are block-local.
template <bool GELU, bool HAS_SCALE, bool HAS_RES, bool DUAL, int KB, bool SECOND>
__global__ void ln_k(const float4* __restrict__ in1, const float4* __restrict__ in2,
                     long kstr4, long off2,
                     const float* __restrict__ scale, const float* __restrict__ bias,
                     const float4* __restrict__ res,
                     float4* __restrict__ out1, float4* __restrict__ out2,
                     const float* __restrict__ bias2, float4* __restrict__ out3) {
  const int row = blockIdx.x, tid = threadIdx.x;
  const int C = blockDim.x * 4;
  const long base = (long)row * blockDim.x + tid;

  float4 p;
  if (KB == 0) {
    p = in1[base];
  } else {
    p = make_float4(0.f, 0.f, 0.f, 0.f);
    #pragma unroll
    for (int k = 0; k < KB; k++) {
      float4 q = in1[(long)k * kstr4 + base];
      p.x += q.x; p.y += q.y; p.z += q.z; p.w += q.w;
    }
  }
  if (GELU) {
    float4 vv;
    if (KB == 0) {
      vv = in2[base];
    } else {
      vv = make_float4(0.f, 0.f, 0.f, 0.f);
      #pragma unroll
      for (int k = 0; k < KB; k++) {
        float4 q = in1[(long)k * kstr4 + off2 + base];
        vv.x += q.x; vv.y += q.y; vv.z += q.z; vv.w += q.w;
      }
    }
    p.x = gelu_f(p.x) * vv.x; p.y = gelu_f(p.y) * vv.y;
    p.z = gelu_f(p.z) * vv.z; p.w = gelu_f(p.w) * vv.w;
  }
  float s  = p.x + p.y + p.z + p.w;
  float s2 = p.x * p.x + p.y * p.y + p.z * p.z + p.w * p.w;

  __shared__ float rs[16], rs2[16];
  int lane = tid & 63, w = tid >> 6;
  #pragma unroll
  for (int o = 32; o; o >>= 1) { s += __shfl_down(s, o, 64); s2 += __shfl_down(s2, o, 64); }
  if (lane == 0) { rs[w] = s; rs2[w] = s2; }
  __syncthreads();
  if (tid == 0) {
    float ts = 0.f, ts2 = 0.f;
    int nw = blockDim.x >> 6;
    for (int i = 0; i < nw; i++) { ts += rs[i]; ts2 += rs2[i]; }
    float mu = ts / C;
    float var = ts2 / C - mu * mu;
    rs[0]  = mu;
    rs2[0] = rsqrtf(var + 1e-6f);
  }
  __syncthreads();
  const float mu = rs[0], rstd = rs2[0];

  float4 o;
  o.x = (p.x - mu) * rstd; o.y = (p.y - mu) * rstd;
  o.z = (p.z - mu) * rstd; o.w = (p.w - mu) * rstd;
  if (HAS_SCALE) {
    float4 sc4 = ((const float4*)scale)[tid];
    o.x *= sc4.x; o.y *= sc4.y; o.z *= sc4.z; o.w *= sc4.w;
  }
  float4 b4 = ((const float4*)bias)[tid];
  o.x += b4.x; o.y += b4.y; o.z += b4.z; o.w += b4.w;
  if (HAS_RES) {
    float4 r4 = res[base];
    o.x += r4.x; o.y += r4.y; o.z += r4.z; o.w += r4.w;
  }
  out1[base] = o;
  if (DUAL) out2[base] = o;

  if (SECOND) {
    // chained LN of the row just produced (scale=None, bias=bias2)
    float t1 = o.x + o.y + o.z + o.w;
    float t2 = o.x * o.x + o.y * o.y + o.z * o.z + o.w * o.w;
    #pragma unroll
    for (int q = 32; q; q >>= 1) { t1 += __shfl_down(t1, q, 64); t2 += __shfl_down(t2, q, 64); }
    __syncthreads();                       // protect rs reuse (phase-1 reads done)
    if (lane == 0) { rs[w] = t1; rs2[w] = t2; }
    __syncthreads();
    if (tid == 0) {
      float ts = 0.f, ts2 = 0.f;
      int nw = blockDim.x >> 6;
      for (int i = 0; i < nw; i++) { ts += rs[i]; ts2 += rs2[i]; }
      float mu2 = ts / C;
      float var2 = ts2 / C - mu2 * mu2;
      rs[0]  = mu2;
      rs2[0] = rsqrtf(var2 + 1e-6f);
    }
    __syncthreads();
    const float mu2 = rs[0], rstd2 = rs2[0];
    float4 bb = ((const float4*)bias2)[tid];
    float4 o2;
    o2.x = (o.x - mu2) * rstd2 + bb.x; o2.y = (o.y - mu2) * rstd2 + bb.y;
    o2.z = (o.z - mu2) * rstd2 + bb.z; o2.w = (o.w - mu2) * rstd2 + bb.w;
    out3[base] = o2;
  }
}

// ---------------- M=64 projection, atomic-free split-K ----------------
// NT=512: 32 n-quads x 16 m-groups(4 rows) -> 2 waves/SIMD (latency hiding; the
// 256-thr version ran 1 wave/SIMD at grid=256 blocks with loads fully exposed).
// grid (N/128, K/kchunk). XP>1: X is a partial arena (stride xstr floats),
// staging sums XP partials on the fly (L2-resident).
template <int NW, int XP, int NT>
__global__ __launch_bounds__(NT)
void proj_k(const float* __restrict__ X, long xstr,
            const float* __restrict__ W0, const float* __restrict__ W1,
            const float* __restrict__ W2,
            float* __restrict__ P, int K, int N, int kchunk) {
  __shared__ float Xs[64 * 64];
  constexpr int MG = NT / 32;          // m-groups per block
  constexpr int RG = 64 / MG;          // rows per group
  const int nq = threadIdx.x & 31;
  const int m0 = (threadIdx.x >> 5) * RG;
  const int n  = blockIdx.x * 128 + nq * 4;
  const int kbase = blockIdx.y * kchunk;

  f32x4_t acc[NW][RG];
  #pragma unroll
  for (int wsel = 0; wsel < NW; wsel++)
    #pragma unroll
    for (int i = 0; i < RG; i++) acc[wsel][i] = (f32x4_t){0.f, 0.f, 0.f, 0.f};

  for (int k0 = kbase; k0 < kbase + kchunk; k0 += 64) {
    __syncthreads();
    #pragma unroll
    for (int j = 0; j < 4096 / NT; j++) {
      int e = threadIdx.x + j * NT;        // e = m*64 + kk  (coalesced global read)
      long off = (long)(e >> 6) * K + k0 + (e & 63);
      float sx = X[off];
      if (XP > 1) {
        #pragma unroll
        for (int k = 1; k < XP; k++) sx += X[(long)k * xstr + off];
      }
      Xs[e] = sx;
    }
    __syncthreads();
    #pragma unroll 4
    for (int kk = 0; kk < 64; kk++) {
      const long wrow = (long)(k0 + kk) * N + n;
      f32x4_t w4[NW];
      w4[0] = *(const f32x4_t*)(W0 + wrow);
      if (NW > 1) w4[1] = *(const f32x4_t*)(W1 + wrow);
      if (NW > 2) w4[2] = *(const f32x4_t*)(W2 + wrow);
      #pragma unroll
      for (int i = 0; i < RG; i++) {
        float xm = Xs[(m0 + i) * 64 + kk];   // 2-way LDS broadcast (free)
        #pragma unroll
        for (int wsel = 0; wsel < NW; wsel++) acc[wsel][i] += xm * w4[wsel];
      }
    }
  }
  float* base = P + (long)blockIdx.y * ((long)NW * 64 * N);
  #pragma unroll
  for (int wsel = 0; wsel < NW; wsel++) {
    #pragma unroll
    for (int i = 0; i < RG; i++) {
      *(f32x4_t*)(base + ((long)wsel * 64 + m0 + i) * N + n) = acc[wsel][i];
    }
  }
}

// ---------------- split-K reduce: Y[e] (+)= sum_k P[k*n4 + e] ----------------
template <bool ACCUM>
__global__ void reduce_k(const float4* __restrict__ P, float4* __restrict__ Y,
                         int KB, long n4) {
  long i = (long)blockIdx.x * blockDim.x + threadIdx.x;
  if (i >= n4) return;
  float4 s = ACCUM ? Y[i] : make_float4(0.f, 0.f, 0.f, 0.f);
  for (int k = 0; k < KB; k++) {
    float4 p = P[(long)k * n4 + i];
    s.x += p.x; s.y += p.y; s.z += p.z; s.w += p.w;
  }
  Y[i] = s;
}

// ---------------- self-attention (Q=1, fp32 cache): one wave per (b,h) ----------------
__global__ void attn_k(const float* __restrict__ Q, const float* __restrict__ Kc,
                       const float* __restrict__ Vc, float* __restrict__ O,
                       const int* __restrict__ tokp, int L, long bstride, float scale) {
  const int b = blockIdx.x, h = blockIdx.y;
  const int lane = threadIdx.x;                 // 64 threads = 1 wave
  __shared__ float sc[256];
  const float* qp = Q + (long)b * Ee + h * Dd;  // wave-uniform -> scalar loads
  const int n = *tokp + 1;

  float mx = -3.0e38f;
  for (int pos = lane; pos < n; pos += 64) {
    const float* kr = Kc + (long)b * bstride + (long)pos * Ee + h * Dd;
    float acc = 0.f;
    #pragma unroll
    for (int j = 0; j < 16; j++) {
      float4 kv = *(const float4*)(kr + j * 4);
      acc += qp[j*4+0]*kv.x + qp[j*4+1]*kv.y + qp[j*4+2]*kv.z + qp[j*4+3]*kv.w;
    }
    float s = acc * scale;
    sc[pos] = s;
    mx = fmaxf(mx, s);
  }
  __syncthreads();
  #pragma unroll
  for (int o = 32; o; o >>= 1) mx = fmaxf(mx, __shfl_down(mx, o, 64));
  mx = __shfl(mx, 0, 64);

  float sum = 0.f;
  for (int pos = lane; pos < n; pos += 64) {
    float e = expf(sc[pos] - mx);
    sc[pos] = e;
    sum += e;
  }
  __syncthreads();
  #pragma unroll
  for (int o = 32; o; o >>= 1) sum += __shfl_down(sum, o, 64);
  sum = __shfl(sum, 0, 64);
  const float inv = 1.0f / sum;

  const float* vbase = Vc + (long)b * bstride + h * Dd + lane;
  float acc = 0.f;
  int pos = 0;
  for (; pos + 8 <= n; pos += 8) {
    #pragma unroll
    for (int u = 0; u < 8; u++)
      acc += sc[pos + u] * vbase[(long)(pos + u) * Ee];
  }
  for (; pos < n; pos++) acc += sc[pos] * vbase[(long)pos * Ee];
  O[(long)b * Ee + h * Dd + lane] = acc * inv;
}

// =====================================================================================
// Cross-attention, rank-1-per-batch restructure (Q=1 decode):
//   scores[b,h,t] = (q_h . k_ca[:,h]^T) . enc[b,t,:]   -> never materialize ek (34 GF)
//   out[b,h,:]    = (P[b,h,:] @ enc_b) @ v_ca[:,h]     -> never materialize ev (34 GF)
// =====================================================================================

// A[b,h,e] = 0.125 * sum_c q2[b, h*64+c] * k_ca[e, h*64+c]
// grid (H=32, E/128=16), 256 threads. Per-head 64x128x64 GEMM.
__global__ __launch_bounds__(256)
void headA_k(const float* __restrict__ Q, const float* __restrict__ Kca,
             float* __restrict__ A) {
  const int h  = blockIdx.x;
  const int e0 = blockIdx.y * 128;
  __shared__ float Qs[64][64];     // [b][c]
  __shared__ float Kt[64][132];    // [c][e], +4 pad keeps 16B alignment + spreads banks
  const int tid = threadIdx.x;

  #pragma unroll
  for (int j = 0; j < 16; j++) {
    int idx = tid + j * 256;                       // 4096 elems
    Qs[idx >> 6][idx & 63] = Q[(long)(idx >> 6) * Ee + h * 64 + (idx & 63)];
  }
  #pragma unroll
  for (int j = 0; j < 32; j++) {
    int idx = tid + j * 256;                       // 8192 elems
    int r = idx >> 6, c = idx & 63;                // coalesced global read
    Kt[c][r] = Kca[(long)(e0 + r) * Ee + h * 64 + c];
  }
  __syncthreads();

  const int nq = tid & 31, m0 = (tid >> 5) * 8;
  f32x4_t acc[8];
  #pragma unroll
  for (int i = 0; i < 8; i++) acc[i] = (f32x4_t){0.f, 0.f, 0.f, 0.f};
  #pragma unroll 8
  for (int c = 0; c < 64; c++) {
    f32x4_t w4 = *(const f32x4_t*)&Kt[c][nq * 4];  // contiguous 512B/half-wave: no conflict
    #pragma unroll
    for (int i = 0; i < 8; i++) acc[i] += Qs[m0 + i][c] * w4;
  }
  #pragma unroll
  for (int i = 0; i < 8; i++)
    *(f32x4_t*)&A[((long)(m0 + i) * Hh + h) * Ee + e0 + nq * 4] = acc[i] * 0.125f;
}

// scores + softmax: P[b,h,t] = softmax_t( sum_e A[b,h,e]*enc[b,t,e] + maskbias )
// grid (B=64, 2 head-groups of 16), 512 threads: wave w owns heads {hg*16+w, hg*16+w+8}.
// 16 heads/block halves enc re-reads vs the 4-group version (134 -> 67 MB).
__global__ __launch_bounds__(512)
void sm_k(const float* __restrict__ A, const float* __restrict__ enc,
          const int* __restrict__ mask, float* __restrict__ P) {
  const int b = blockIdx.x, hg = blockIdx.y;
  __shared__ float Es[64][65];     // [t][e-chunk], +1 pad -> 2-way on read (free)
  __shared__ float As[16][64];
  const int tid = threadIdx.x;
  const int t = tid & 63, h2 = tid >> 6;   // h2 = wave index (0..7)

  float s0 = 0.f, s1 = 0.f;
  for (int e0 = 0; e0 < Ee; e0 += 64) {
    __syncthreads();
    #pragma unroll
    for (int j = 0; j < 8; j++) {
      int idx = tid + j * 512;
      Es[idx >> 6][idx & 63] = enc[((long)b * Tt + (idx >> 6)) * Ee + e0 + (idx & 63)];
    }
    #pragma unroll
    for (int j = 0; j < 2; j++) {
      int idx = tid + j * 512;
      As[idx >> 6][idx & 63] =
          A[((long)b * Hh + hg * 16 + (idx >> 6)) * Ee + e0 + (idx & 63)];
    }
    __syncthreads();
    #pragma unroll 8
    for (int e = 0; e < 64; e++) {
      float es = Es[t][e];                         // As wave-uniform bcast
      s0 += As[h2][e] * es;
      s1 += As[h2 + 8][e] * es;
    }
  }

  if (mask[(long)b * Tt + t] == 0) { s0 = -1e30f; s1 = -1e30f; }
  float m0v = s0, m1v = s1;
  #pragma unroll
  for (int o = 32; o; o >>= 1) {
    m0v = fmaxf(m0v, __shfl_xor(m0v, o, 64));
    m1v = fmaxf(m1v, __shfl_xor(m1v, o, 64));
  }
  float p0 = expf(s0 - m0v), p1 = expf(s1 - m1v);
  float d0 = p0, d1 = p1;
  #pragma unroll
  for (int o = 32; o; o >>= 1) {
    d0 += __shfl_xor(d0, o, 64);
    d1 += __shfl_xor(d1, o, 64);
  }
  P[((long)b * Hh + hg * 16 + h2) * Tt + t]     = p0 / d0;
  P[((long)b * Hh + hg * 16 + h2 + 8) * Tt + t] = p1 / d1;
}

// ctx[b,h,e] = sum_t P[b,h,t] * enc[b,t,e]
// grid (B=64, E/256=8), 256 threads: thread owns column e0+tid for all 32 heads.
__global__ __launch_bounds__(256)
void ctxB_k(const float* __restrict__ P, const float* __restrict__ enc,
            float* __restrict__ C) {
  const int b = blockIdx.x, e0 = blockIdx.y * 256;
  __shared__ float Ps[32][64];
  const int tid = threadIdx.x;
  #pragma unroll
  for (int j = 0; j < 8; j++) {
    int idx = tid + j * 256;
    Ps[idx >> 6][idx & 63] = P[(long)b * (Hh * Tt) + idx];
  }
  __syncthreads();

  float acc[32];
  #pragma unroll
  for (int h = 0; h < 32; h++) acc[h] = 0.f;
  const float* ep = enc + (long)b * Tt * Ee + e0 + tid;
  for (int t0 = 0; t0 < Tt; t0 += 4) {
    float ev0 = ep[(long)(t0 + 0) * Ee];
    float ev1 = ep[(long)(t0 + 1) * Ee];
    float ev2 = ep[(long)(t0 + 2) * Ee];
    float ev3 = ep[(long)(t0 + 3) * Ee];
    #pragma unroll
    for (int h = 0; h < 32; h++) {
      f32x4_t p4 = *(const f32x4_t*)&Ps[h][t0];    // wave-uniform b128 broadcast
      acc[h] += p4[0] * ev0 + p4[1] * ev1 + p4[2] * ev2 + p4[3] * ev3;
    }
  }
  #pragma unroll
  for (int h = 0; h < 32; h++)
    C[((long)b * Hh + h) * Ee + e0 + tid] = acc[h];
}

// cb-partials[kb][b, h*64+c] = sum_{e in chunk} ctx[b,h,e] * v_ca[e, h*64+c]
// grid (H=32, 8 k-chunks of 256), 256 threads = 16 n-quads x 16 m-groups(4 rows).
__global__ __launch_bounds__(256)
void ctxC_k(const float* __restrict__ C, const float* __restrict__ Vca,
            float* __restrict__ Pout) {
  const int h  = blockIdx.x;
  const int kb = blockIdx.y;
  __shared__ float Xs[64][65];     // [b][kk], pad kills 16-way on scalar read
  __shared__ float Ws[64][64];     // [kk][c]
  const int tid = threadIdx.x;
  const int nq = tid & 15, m0 = (tid >> 4) * 4;

  f32x4_t acc[4];
  #pragma unroll
  for (int i = 0; i < 4; i++) acc[i] = (f32x4_t){0.f, 0.f, 0.f, 0.f};

  for (int k0 = kb * 256; k0 < kb * 256 + 256; k0 += 64) {
    __syncthreads();
    #pragma unroll
    for (int j = 0; j < 16; j++) {
      int idx = tid + j * 256;
      int r = idx >> 6, cc = idx & 63;
      Xs[r][cc] = C[((long)r * Hh + h) * Ee + k0 + cc];
      Ws[r][cc] = Vca[(long)(k0 + r) * Ee + h * 64 + cc];
    }
    __syncthreads();
    #pragma unroll 4
    for (int kk = 0; kk < 64; kk++) {
      f32x4_t w4 = *(const f32x4_t*)&Ws[kk][nq * 4];
      #pragma unroll
      for (int i = 0; i < 4; i++) acc[i] += Xs[m0 + i][kk] * w4;
    }
  }
  #pragma unroll
  for (int i = 0; i < 4; i++)
    *(f32x4_t*)&Pout[((long)kb * 64 + m0 + i) * Ee + h * 64 + nq * 4] = acc[i];
}

extern "C" void kernel_launch(void* const* d_in, const int* in_sizes, int n_in,
                              void* d_out, int out_size, void* d_ws, size_t ws_size,
                              hipStream_t stream) {
  const float* dec    = (const float*)d_in[0];
  const float* enc    = (const float*)d_in[1];
  const float* astate = (const float*)d_in[2];
  const int*   amask  = (const int*)d_in[3];
  const int*   tokp   = (const int*)d_in[4];
  const float* ln_pre_sa_b = (const float*)d_in[5];
  const float* q_sa = (const float*)d_in[6];
  const float* k_sa = (const float*)d_in[7];
  const float* v_sa = (const float*)d_in[8];
  const float* o_sa = (const float*)d_in[9];
  const float* ln_sa_s = (const float*)d_in[10];
  const float* ln_sa_b = (const float*)d_in[11];
  const float* ln_pre_ca_b = (const float*)d_in[12];
  const float* q_ca = (const float*)d_in[13];
  const float* k_ca = (const float*)d_in[14];
  const float* v_ca = (const float*)d_in[15];
  const float* o_ca = (const float*)d_in[16];
  const float* ln_ca_s = (const float*)d_in[17];
  const float* ln_ca_b = (const float*)d_in[18];
  const float* glu_ln0_b = (const float*)d_in[19];
  const float* fc0 = (const float*)d_in[20];
  const float* fc1 = (const float*)d_in[21];
  const float* glu_ln1_s = (const float*)d_in[22];
  const float* glu_ln1_b = (const float*)d_in[23];
  const float* fc2 = (const float*)d_in[24];

  float* out_dec   = (float*)d_out;
  float* out_state = out_dec + (long)Bb * Ee;

  // ---- workspace carve (floats) ----
  float* qb  = (float*)d_ws;            // qb,kb,vb contiguous (one reduce)
  float* kb  = qb  + 131072;
  float* vb  = kb  + 131072;
  float* q2  = vb  + 131072;
  float* x1  = q2  + 131072;
  float* ab  = x1  + 131072;
  float* ds2 = ab  + 131072;
  float* x3  = ds2 + 131072;
  float* ds3 = x3  + 131072;
  float* zb  = ds3 + 131072;
  float* wvn = zb  + 131072;            // 64*4096
  float* Ab   = wvn + 262144;           // A[b][h][e]   64*32*2048
  float* ctxb = Ab  + 4194304;          // ctx[b][h][e] 64*32*2048
  float* Pb   = ctxb + 4194304;         // P[b][h][t]   64*32*64
  float* arenaA = Pb + 131072;          // split-K partials (max 8x2x64x4096 = 16.8MB)
  float* arenaB = arenaA + 8388608;     // second arena (ctxC partials / fc2 partials)

  // --- self-attention block ---
  ln_k<false,false,false,false,0,false><<<Bb, 512, 0, stream>>>(
      (const float4*)dec, nullptr, 0, 0, nullptr, ln_pre_sa_b, nullptr,
      (float4*)x1, nullptr, nullptr, nullptr);
  proj_k<3,1,512><<<dim3(16, 16), 512, 0, stream>>>(x1, 0, q_sa, k_sa, v_sa,
                                                    arenaA, Ee, Ee, 128);
  reduce_k<false><<<384, 256, 0, stream>>>((const float4*)arenaA, (float4*)qb, 16, 98304);
  copy_state_k<<<4096, 256, 0, stream>>>((const float4*)astate, (float4*)out_state,
                                         (const float4*)kb, (const float4*)vb, tokp);
  attn_k<<<dim3(Bb, Hh), 64, 0, stream>>>(qb, out_state,
      out_state + (long)Bb * Ii * Ee, ab, tokp, Ii, (long)Ii * Ee, 0.125f);
  proj_k<1,1,512><<<dim3(16, 16), 512, 0, stream>>>(ab, 0, o_sa, nullptr, nullptr,
                                                    arenaA, Ee, Ee, 128);
  // fused: reduce(16 partials) + LN + residual + chained LN -> ds2 AND x3
  ln_k<false,true,true,false,16,true><<<Bb, 512, 0, stream>>>(
      (const float4*)arenaA, nullptr, 32768, 0, ln_sa_s, ln_sa_b,
      (const float4*)dec, (float4*)ds2, nullptr, ln_pre_ca_b, (float4*)x3);

  // --- cross-attention block (rank-1 restructure: no ek/ev materialization) ---
  proj_k<1,1,512><<<dim3(16, 16), 512, 0, stream>>>(x3, 0, q_ca, nullptr, nullptr,
                                                    arenaA, Ee, Ee, 128);
  reduce_k<false><<<128, 256, 0, stream>>>((const float4*)arenaA, (float4*)q2, 16, 32768);
  headA_k<<<dim3(Hh, 16), 256, 0, stream>>>(q2, k_ca, Ab);
  sm_k<<<dim3(Bb, 2), 512, 0, stream>>>(Ab, enc, amask, Pb);
  ctxB_k<<<dim3(Bb, 8), 256, 0, stream>>>(Pb, enc, ctxb);
  ctxC_k<<<dim3(Hh, 8), 256, 0, stream>>>(ctxb, v_ca, arenaB);
  // o_ca projection consumes ctxC's 8 partials directly in staging
  proj_k<1,8,512><<<dim3(16, 16), 512, 0, stream>>>(arenaB, 131072, o_ca, nullptr, nullptr,
                                                    arenaA, Ee, Ee, 128);
  // fused: reduce + LN + residual, dual-output (ds3, out_dec) + chained LN -> zb
  ln_k<false,true,true,true,16,true><<<Bb, 512, 0, stream>>>(
      (const float4*)arenaA, nullptr, 32768, 0, ln_ca_s, ln_ca_b,
      (const float4*)ds2, (float4*)ds3, (float4*)out_dec, glu_ln0_b, (float4*)zb);

  // --- GLU block ---
  proj_k<2,1,512><<<dim3(32, 8), 512, 0, stream>>>(zb, 0, fc0, fc1, nullptr,
                                                   arenaA, Ee, Gg, 256);
  // fused: reduce(8 partials of w0,v1) + GELU-GLU + LN
  ln_k<true,true,false,false,8,false><<<Bb, 1024, 0, stream>>>(
      (const float4*)arenaA, nullptr, 131072, 65536, glu_ln1_s, glu_ln1_b,
      nullptr, (float4*)wvn, nullptr, nullptr, nullptr);
  proj_k<1,1,512><<<dim3(16, 16), 512, 0, stream>>>(wvn, 0, fc2, nullptr, nullptr,
                                                    arenaB, Gg, Ee, 256);
  reduce_k<true><<<128, 256, 0, stream>>>((const float4*)arenaB, (float4*)out_dec, 16, 32768);
}

// Round 4
// 1108.513 us; speedup vs baseline: 1.2373x; 1.2373x over previous
//
#include <hip/hip_runtime.h>

// Sizes fixed by the problem
#define Bb   64
#define Ee   2048
#define Tt   64
#define Gg   4096
#define Ii   256
#define Hh   32
#define Dd   64

using f32x4_t  = __attribute__((ext_vector_type(4))) float;

__device__ __forceinline__ float gelu_f(float x) {
  return 0.5f * x * (1.0f + erff(x * 0.70710678118654752f));
}

// ---------------- state copy fused with KV-cache update at token_index ----------------
__global__ void copy_state_k(const float4* __restrict__ src, float4* __restrict__ dst,
                             const float4* __restrict__ kb, const float4* __restrict__ vb,
                             const int* __restrict__ tokp) {
  const int t = *tokp;
  const long n4 = (long)128 * Ii * (Ee / 4);
  long i = (long)blockIdx.x * blockDim.x + threadIdx.x;
  const long stride = (long)gridDim.x * blockDim.x;
  for (; i < n4; i += stride) {
    long row = i >> 9;                 // / (Ee/4)
    int tt = (int)(row & (Ii - 1));
    float4 v;
    if (tt == t) {                     // wave-uniform (rows are 512 float4 wide)
      int bh  = (int)(row >> 8);       // 0..127
      int col = (int)(i & 511);
      const float4* s = (bh < Bb) ? kb : vb;
      v = s[(long)(bh & (Bb - 1)) * (Ee / 4) + col];
    } else {
      v = src[i];
    }
    dst[i] = v;
  }
}

// ---------------- layer norm, fused split-K reduce + optional chained 2nd LN ----------------
// KB==0: read in1[base]. KB>0: row value = sum_k in1[k*kstr4 + base] (partial arena).
// GELU+KB>0: second operand = sum_k in1[k*kstr4 + off2 + base].
// SECOND: also emit out3 = LN(out1_row, scale=None, bias2) -- stats are block-local.
template <bool GELU, bool HAS_SCALE, bool HAS_RES, bool DUAL, int KB, bool SECOND>
__global__ void ln_k(const float4* __restrict__ in1, const float4* __restrict__ in2,
                     long kstr4, long off2,
                     const float* __restrict__ scale, const float* __restrict__ bias,
                     const float4* __restrict__ res,
                     float4* __restrict__ out1, float4* __restrict__ out2,
                     const float* __restrict__ bias2, float4* __restrict__ out3) {
  const int row = blockIdx.x, tid = threadIdx.x;
  const int C = blockDim.x * 4;
  const long base = (long)row * blockDim.x + tid;

  float4 p;
  if (KB == 0) {
    p = in1[base];
  } else {
    p = make_float4(0.f, 0.f, 0.f, 0.f);
    #pragma unroll
    for (int k = 0; k < KB; k++) {
      float4 q = in1[(long)k * kstr4 + base];
      p.x += q.x; p.y += q.y; p.z += q.z; p.w += q.w;
    }
  }
  if (GELU) {
    float4 vv;
    if (KB == 0) {
      vv = in2[base];
    } else {
      vv = make_float4(0.f, 0.f, 0.f, 0.f);
      #pragma unroll
      for (int k = 0; k < KB; k++) {
        float4 q = in1[(long)k * kstr4 + off2 + base];
        vv.x += q.x; vv.y += q.y; vv.z += q.z; vv.w += q.w;
      }
    }
    p.x = gelu_f(p.x) * vv.x; p.y = gelu_f(p.y) * vv.y;
    p.z = gelu_f(p.z) * vv.z; p.w = gelu_f(p.w) * vv.w;
  }
  float s  = p.x + p.y + p.z + p.w;
  float s2 = p.x * p.x + p.y * p.y + p.z * p.z + p.w * p.w;

  __shared__ float rs[16], rs2[16];
  int lane = tid & 63, w = tid >> 6;
  #pragma unroll
  for (int o = 32; o; o >>= 1) { s += __shfl_down(s, o, 64); s2 += __shfl_down(s2, o, 64); }
  if (lane == 0) { rs[w] = s; rs2[w] = s2; }
  __syncthreads();
  if (tid == 0) {
    float ts = 0.f, ts2 = 0.f;
    int nw = blockDim.x >> 6;
    for (int i = 0; i < nw; i++) { ts += rs[i]; ts2 += rs2[i]; }
    float mu = ts / C;
    float var = ts2 / C - mu * mu;
    rs[0]  = mu;
    rs2[0] = rsqrtf(var + 1e-6f);
  }
  __syncthreads();
  const float mu = rs[0], rstd = rs2[0];

  float4 o;
  o.x = (p.x - mu) * rstd; o.y = (p.y - mu) * rstd;
  o.z = (p.z - mu) * rstd; o.w = (p.w - mu) * rstd;
  if (HAS_SCALE) {
    float4 sc4 = ((const float4*)scale)[tid];
    o.x *= sc4.x; o.y *= sc4.y; o.z *= sc4.z; o.w *= sc4.w;
  }
  float4 b4 = ((const float4*)bias)[tid];
  o.x += b4.x; o.y += b4.y; o.z += b4.z; o.w += b4.w;
  if (HAS_RES) {
    float4 r4 = res[base];
    o.x += r4.x; o.y += r4.y; o.z += r4.z; o.w += r4.w;
  }
  out1[base] = o;
  if (DUAL) out2[base] = o;

  if (SECOND) {
    // chained LN of the row just produced (scale=None, bias=bias2)
    float t1 = o.x + o.y + o.z + o.w;
    float t2 = o.x * o.x + o.y * o.y + o.z * o.z + o.w * o.w;
    #pragma unroll
    for (int q = 32; q; q >>= 1) { t1 += __shfl_down(t1, q, 64); t2 += __shfl_down(t2, q, 64); }
    __syncthreads();                       // protect rs reuse (phase-1 reads done)
    if (lane == 0) { rs[w] = t1; rs2[w] = t2; }
    __syncthreads();
    if (tid == 0) {
      float ts = 0.f, ts2 = 0.f;
      int nw = blockDim.x >> 6;
      for (int i = 0; i < nw; i++) { ts += rs[i]; ts2 += rs2[i]; }
      float mu2 = ts / C;
      float var2 = ts2 / C - mu2 * mu2;
      rs[0]  = mu2;
      rs2[0] = rsqrtf(var2 + 1e-6f);
    }
    __syncthreads();
    const float mu2 = rs[0], rstd2 = rs2[0];
    float4 bb = ((const float4*)bias2)[tid];
    float4 o2;
    o2.x = (o.x - mu2) * rstd2 + bb.x; o2.y = (o.y - mu2) * rstd2 + bb.y;
    o2.z = (o.z - mu2) * rstd2 + bb.z; o2.w = (o.w - mu2) * rstd2 + bb.w;
    out3[base] = o2;
  }
}

// ---------------- M=64 projection, atomic-free split-K ----------------
// block 256 = 32 n-quads x 8 m-groups(8 rows); grid (N/128, K/128).
// (round-3 lesson: 512-thr/4-row variant doubles the weight VMEM issue count
// per FLOP -> ~2x slower; weight loads dominate, rows/thread must stay high.)
// XP>1: X is a partial arena (stride xstr floats), staging sums XP partials
// on the fly (L2-resident).
template <int NW, int XP>
__global__ __launch_bounds__(256)
void proj_k(const float* __restrict__ X, long xstr,
            const float* __restrict__ W0, const float* __restrict__ W1,
            const float* __restrict__ W2,
            float* __restrict__ P, int K, int N) {
  __shared__ float Xs[64 * 64];
  const int nq = threadIdx.x & 31;
  const int m0 = (threadIdx.x >> 5) * 8;
  const int n  = blockIdx.x * 128 + nq * 4;
  const int kbase = blockIdx.y * 128;

  f32x4_t acc[NW][8];
  #pragma unroll
  for (int wsel = 0; wsel < NW; wsel++)
    #pragma unroll
    for (int i = 0; i < 8; i++) acc[wsel][i] = (f32x4_t){0.f, 0.f, 0.f, 0.f};

  for (int k0 = kbase; k0 < kbase + 128; k0 += 64) {
    __syncthreads();
    #pragma unroll
    for (int j = 0; j < 16; j++) {
      int e = threadIdx.x + j * 256;        // e = m*64 + kk  (coalesced global read)
      long off = (long)(e >> 6) * K + k0 + (e & 63);
      float sx = X[off];
      if (XP > 1) {
        #pragma unroll
        for (int k = 1; k < XP; k++) sx += X[(long)k * xstr + off];
      }
      Xs[e] = sx;
    }
    __syncthreads();
    #pragma unroll 4
    for (int kk = 0; kk < 64; kk++) {
      const long wrow = (long)(k0 + kk) * N + n;
      f32x4_t w4[NW];
      w4[0] = *(const f32x4_t*)(W0 + wrow);
      if (NW > 1) w4[1] = *(const f32x4_t*)(W1 + wrow);
      if (NW > 2) w4[2] = *(const f32x4_t*)(W2 + wrow);
      #pragma unroll
      for (int i = 0; i < 8; i++) {
        float xm = Xs[(m0 + i) * 64 + kk];   // 2-way LDS broadcast (free)
        #pragma unroll
        for (int wsel = 0; wsel < NW; wsel++) acc[wsel][i] += xm * w4[wsel];
      }
    }
  }
  float* base = P + (long)blockIdx.y * ((long)NW * 64 * N);
  #pragma unroll
  for (int wsel = 0; wsel < NW; wsel++) {
    #pragma unroll
    for (int i = 0; i < 8; i++) {
      *(f32x4_t*)(base + ((long)wsel * 64 + m0 + i) * N + n) = acc[wsel][i];
    }
  }
}

// ---------------- split-K reduce: Y[e] (+)= sum_k P[k*n4 + e] ----------------
template <bool ACCUM>
__global__ void reduce_k(const float4* __restrict__ P, float4* __restrict__ Y,
                         int KB, long n4) {
  long i = (long)blockIdx.x * blockDim.x + threadIdx.x;
  if (i >= n4) return;
  float4 s = ACCUM ? Y[i] : make_float4(0.f, 0.f, 0.f, 0.f);
  for (int k = 0; k < KB; k++) {
    float4 p = P[(long)k * n4 + i];
    s.x += p.x; s.y += p.y; s.z += p.z; s.w += p.w;
  }
  Y[i] = s;
}

// ---------------- self-attention (Q=1, fp32 cache): one wave per (b,h) ----------------
__global__ void attn_k(const float* __restrict__ Q, const float* __restrict__ Kc,
                       const float* __restrict__ Vc, float* __restrict__ O,
                       const int* __restrict__ tokp, int L, long bstride, float scale) {
  const int b = blockIdx.x, h = blockIdx.y;
  const int lane = threadIdx.x;                 // 64 threads = 1 wave
  __shared__ float sc[256];
  const float* qp = Q + (long)b * Ee + h * Dd;  // wave-uniform -> scalar loads
  const int n = *tokp + 1;

  float mx = -3.0e38f;
  for (int pos = lane; pos < n; pos += 64) {
    const float* kr = Kc + (long)b * bstride + (long)pos * Ee + h * Dd;
    float acc = 0.f;
    #pragma unroll
    for (int j = 0; j < 16; j++) {
      float4 kv = *(const float4*)(kr + j * 4);
      acc += qp[j*4+0]*kv.x + qp[j*4+1]*kv.y + qp[j*4+2]*kv.z + qp[j*4+3]*kv.w;
    }
    float s = acc * scale;
    sc[pos] = s;
    mx = fmaxf(mx, s);
  }
  __syncthreads();
  #pragma unroll
  for (int o = 32; o; o >>= 1) mx = fmaxf(mx, __shfl_down(mx, o, 64));
  mx = __shfl(mx, 0, 64);

  float sum = 0.f;
  for (int pos = lane; pos < n; pos += 64) {
    float e = expf(sc[pos] - mx);
    sc[pos] = e;
    sum += e;
  }
  __syncthreads();
  #pragma unroll
  for (int o = 32; o; o >>= 1) sum += __shfl_down(sum, o, 64);
  sum = __shfl(sum, 0, 64);
  const float inv = 1.0f / sum;

  const float* vbase = Vc + (long)b * bstride + h * Dd + lane;
  float acc = 0.f;
  int pos = 0;
  for (; pos + 8 <= n; pos += 8) {
    #pragma unroll
    for (int u = 0; u < 8; u++)
      acc += sc[pos + u] * vbase[(long)(pos + u) * Ee];
  }
  for (; pos < n; pos++) acc += sc[pos] * vbase[(long)pos * Ee];
  O[(long)b * Ee + h * Dd + lane] = acc * inv;
}

// =====================================================================================
// Cross-attention, rank-1-per-batch restructure (Q=1 decode):
//   scores[b,h,t] = (q_h . k_ca[:,h]^T) . enc[b,t,:]   -> never materialize ek (34 GF)
//   out[b,h,:]    = (P[b,h,:] @ enc_b) @ v_ca[:,h]     -> never materialize ev (34 GF)
// =====================================================================================

// A[b,h,e] = 0.125 * sum_c q2[b, h*64+c] * k_ca[e, h*64+c]
// grid (H=32, E/128=16), 256 threads. Per-head 64x128x64 GEMM.
__global__ __launch_bounds__(256)
void headA_k(const float* __restrict__ Q, const float* __restrict__ Kca,
             float* __restrict__ A) {
  const int h  = blockIdx.x;
  const int e0 = blockIdx.y * 128;
  __shared__ float Qs[64][64];     // [b][c]
  __shared__ float Kt[64][132];    // [c][e], +4 pad keeps 16B alignment + spreads banks
  const int tid = threadIdx.x;

  #pragma unroll
  for (int j = 0; j < 16; j++) {
    int idx = tid + j * 256;                       // 4096 elems
    Qs[idx >> 6][idx & 63] = Q[(long)(idx >> 6) * Ee + h * 64 + (idx & 63)];
  }
  #pragma unroll
  for (int j = 0; j < 32; j++) {
    int idx = tid + j * 256;                       // 8192 elems
    int r = idx >> 6, c = idx & 63;                // coalesced global read
    Kt[c][r] = Kca[(long)(e0 + r) * Ee + h * 64 + c];
  }
  __syncthreads();

  const int nq = tid & 31, m0 = (tid >> 5) * 8;
  f32x4_t acc[8];
  #pragma unroll
  for (int i = 0; i < 8; i++) acc[i] = (f32x4_t){0.f, 0.f, 0.f, 0.f};
  #pragma unroll 8
  for (int c = 0; c < 64; c++) {
    f32x4_t w4 = *(const f32x4_t*)&Kt[c][nq * 4];  // contiguous 512B/half-wave: no conflict
    #pragma unroll
    for (int i = 0; i < 8; i++) acc[i] += Qs[m0 + i][c] * w4;
  }
  #pragma unroll
  for (int i = 0; i < 8; i++)
    *(f32x4_t*)&A[((long)(m0 + i) * Hh + h) * Ee + e0 + nq * 4] = acc[i] * 0.125f;
}

// scores + softmax: P[b,h,t] = softmax_t( sum_e A[b,h,e]*enc[b,t,e] + maskbias )
// grid (B=64, 4 head-groups of 8), 512 threads: wave w owns head hg*8+w, lane = t.
// (round-3 lesson: 2 head-groups = 128 blocks leaves half the CUs idle -> 4 groups.)
__global__ __launch_bounds__(512)
void sm_k(const float* __restrict__ A, const float* __restrict__ enc,
          const int* __restrict__ mask, float* __restrict__ P) {
  const int b = blockIdx.x, hg = blockIdx.y;
  __shared__ float Es[64][65];     // [t][e-chunk], +1 pad -> 2-way on read (free)
  __shared__ float As[8][64];
  const int tid = threadIdx.x;
  const int t = tid & 63, h2 = tid >> 6;   // h2 = wave index = head within group

  float s = 0.f;
  for (int e0 = 0; e0 < Ee; e0 += 64) {
    __syncthreads();
    #pragma unroll
    for (int j = 0; j < 8; j++) {
      int idx = tid + j * 512;
      Es[idx >> 6][idx & 63] = enc[((long)b * Tt + (idx >> 6)) * Ee + e0 + (idx & 63)];
    }
    As[h2][t] = A[((long)b * Hh + hg * 8 + h2) * Ee + e0 + t];  // 1 row/wave, coalesced
    __syncthreads();
    #pragma unroll 8
    for (int e = 0; e < 64; e++) s += As[h2][e] * Es[t][e];     // As wave-uniform bcast
  }

  if (mask[(long)b * Tt + t] == 0) s = -1e30f;
  float mv = s;
  #pragma unroll
  for (int o = 32; o; o >>= 1) mv = fmaxf(mv, __shfl_xor(mv, o, 64));
  float p = expf(s - mv);
  float d = p;
  #pragma unroll
  for (int o = 32; o; o >>= 1) d += __shfl_xor(d, o, 64);
  P[((long)b * Hh + hg * 8 + h2) * Tt + t] = p / d;
}

// ctx[b,h,e] = sum_t P[b,h,t] * enc[b,t,e]
// grid (B=64, E/256=8), 256 threads: thread owns column e0+tid for all 32 heads.
__global__ __launch_bounds__(256)
void ctxB_k(const float* __restrict__ P, const float* __restrict__ enc,
            float* __restrict__ C) {
  const int b = blockIdx.x, e0 = blockIdx.y * 256;
  __shared__ float Ps[32][64];
  const int tid = threadIdx.x;
  #pragma unroll
  for (int j = 0; j < 8; j++) {
    int idx = tid + j * 256;
    Ps[idx >> 6][idx & 63] = P[(long)b * (Hh * Tt) + idx];
  }
  __syncthreads();

  float acc[32];
  #pragma unroll
  for (int h = 0; h < 32; h++) acc[h] = 0.f;
  const float* ep = enc + (long)b * Tt * Ee + e0 + tid;
  for (int t0 = 0; t0 < Tt; t0 += 4) {
    float ev0 = ep[(long)(t0 + 0) * Ee];
    float ev1 = ep[(long)(t0 + 1) * Ee];
    float ev2 = ep[(long)(t0 + 2) * Ee];
    float ev3 = ep[(long)(t0 + 3) * Ee];
    #pragma unroll
    for (int h = 0; h < 32; h++) {
      f32x4_t p4 = *(const f32x4_t*)&Ps[h][t0];    // wave-uniform b128 broadcast
      acc[h] += p4[0] * ev0 + p4[1] * ev1 + p4[2] * ev2 + p4[3] * ev3;
    }
  }
  #pragma unroll
  for (int h = 0; h < 32; h++)
    C[((long)b * Hh + h) * Ee + e0 + tid] = acc[h];
}

// cb-partials[kb][b, h*64+c] = sum_{e in chunk} ctx[b,h,e] * v_ca[e, h*64+c]
// grid (H=32, 8 k-chunks of 256), 256 threads = 16 n-quads x 16 m-groups(4 rows).
__global__ __launch_bounds__(256)
void ctxC_k(const float* __restrict__ C, const float* __restrict__ Vca,
            float* __restrict__ Pout) {
  const int h  = blockIdx.x;
  const int kb = blockIdx.y;
  __shared__ float Xs[64][65];     // [b][kk], pad kills 16-way on scalar read
  __shared__ float Ws[64][64];     // [kk][c]
  const int tid = threadIdx.x;
  const int nq = tid & 15, m0 = (tid >> 4) * 4;

  f32x4_t acc[4];
  #pragma unroll
  for (int i = 0; i < 4; i++) acc[i] = (f32x4_t){0.f, 0.f, 0.f, 0.f};

  for (int k0 = kb * 256; k0 < kb * 256 + 256; k0 += 64) {
    __syncthreads();
    #pragma unroll
    for (int j = 0; j < 16; j++) {
      int idx = tid + j * 256;
      int r = idx >> 6, cc = idx & 63;
      Xs[r][cc] = C[((long)r * Hh + h) * Ee + k0 + cc];
      Ws[r][cc] = Vca[(long)(k0 + r) * Ee + h * 64 + cc];
    }
    __syncthreads();
    #pragma unroll 4
    for (int kk = 0; kk < 64; kk++) {
      f32x4_t w4 = *(const f32x4_t*)&Ws[kk][nq * 4];
      #pragma unroll
      for (int i = 0; i < 4; i++) acc[i] += Xs[m0 + i][kk] * w4;
    }
  }
  #pragma unroll
  for (int i = 0; i < 4; i++)
    *(f32x4_t*)&Pout[((long)kb * 64 + m0 + i) * Ee + h * 64 + nq * 4] = acc[i];
}

extern "C" void kernel_launch(void* const* d_in, const int* in_sizes, int n_in,
                              void* d_out, int out_size, void* d_ws, size_t ws_size,
                              hipStream_t stream) {
  const float* dec    = (const float*)d_in[0];
  const float* enc    = (const float*)d_in[1];
  const float* astate = (const float*)d_in[2];
  const int*   amask  = (const int*)d_in[3];
  const int*   tokp   = (const int*)d_in[4];
  const float* ln_pre_sa_b = (const float*)d_in[5];
  const float* q_sa = (const float*)d_in[6];
  const float* k_sa = (const float*)d_in[7];
  const float* v_sa = (const float*)d_in[8];
  const float* o_sa = (const float*)d_in[9];
  const float* ln_sa_s = (const float*)d_in[10];
  const float* ln_sa_b = (const float*)d_in[11];
  const float* ln_pre_ca_b = (const float*)d_in[12];
  const float* q_ca = (const float*)d_in[13];
  const float* k_ca = (const float*)d_in[14];
  const float* v_ca = (const float*)d_in[15];
  const float* o_ca = (const float*)d_in[16];
  const float* ln_ca_s = (const float*)d_in[17];
  const float* ln_ca_b = (const float*)d_in[18];
  const float* glu_ln0_b = (const float*)d_in[19];
  const float* fc0 = (const float*)d_in[20];
  const float* fc1 = (const float*)d_in[21];
  const float* glu_ln1_s = (const float*)d_in[22];
  const float* glu_ln1_b = (const float*)d_in[23];
  const float* fc2 = (const float*)d_in[24];

  float* out_dec   = (float*)d_out;
  float* out_state = out_dec + (long)Bb * Ee;

  // ---- workspace carve (floats) ----
  float* qb  = (float*)d_ws;            // qb,kb,vb contiguous (one reduce)
  float* kb  = qb  + 131072;
  float* vb  = kb  + 131072;
  float* q2  = vb  + 131072;
  float* x1  = q2  + 131072;
  float* ab  = x1  + 131072;
  float* ds2 = ab  + 131072;
  float* x3  = ds2 + 131072;
  float* ds3 = x3  + 131072;
  float* zb  = ds3 + 131072;
  float* wvn = zb  + 131072;            // 64*4096
  float* Ab   = wvn + 262144;           // A[b][h][e]   64*32*2048
  float* ctxb = Ab  + 4194304;          // ctx[b][h][e] 64*32*2048
  float* Pb   = ctxb + 4194304;         // P[b][h][t]   64*32*64
  float* arenaA = Pb + 131072;          // split-K partials (max 16x2x64x4096 = 33.5MB)
  float* arenaB = arenaA + 8388608;     // second arena (ctxC partials / fc2 partials)

  // --- self-attention block ---
  ln_k<false,false,false,false,0,false><<<Bb, 512, 0, stream>>>(
      (const float4*)dec, nullptr, 0, 0, nullptr, ln_pre_sa_b, nullptr,
      (float4*)x1, nullptr, nullptr, nullptr);
  proj_k<3,1><<<dim3(16, 16), 256, 0, stream>>>(x1, 0, q_sa, k_sa, v_sa, arenaA, Ee, Ee);
  reduce_k<false><<<384, 256, 0, stream>>>((const float4*)arenaA, (float4*)qb, 16, 98304);
  copy_state_k<<<4096, 256, 0, stream>>>((const float4*)astate, (float4*)out_state,
                                         (const float4*)kb, (const float4*)vb, tokp);
  attn_k<<<dim3(Bb, Hh), 64, 0, stream>>>(qb, out_state,
      out_state + (long)Bb * Ii * Ee, ab, tokp, Ii, (long)Ii * Ee, 0.125f);
  proj_k<1,1><<<dim3(16, 16), 256, 0, stream>>>(ab, 0, o_sa, nullptr, nullptr, arenaA, Ee, Ee);
  // fused: reduce(16 partials) + LN + residual + chained LN -> ds2 AND x3
  ln_k<false,true,true,false,16,true><<<Bb, 512, 0, stream>>>(
      (const float4*)arenaA, nullptr, 32768, 0, ln_sa_s, ln_sa_b,
      (const float4*)dec, (float4*)ds2, nullptr, ln_pre_ca_b, (float4*)x3);

  // --- cross-attention block (rank-1 restructure: no ek/ev materialization) ---
  proj_k<1,1><<<dim3(16, 16), 256, 0, stream>>>(x3, 0, q_ca, nullptr, nullptr, arenaA, Ee, Ee);
  reduce_k<false><<<128, 256, 0, stream>>>((const float4*)arenaA, (float4*)q2, 16, 32768);
  headA_k<<<dim3(Hh, 16), 256, 0, stream>>>(q2, k_ca, Ab);
  sm_k<<<dim3(Bb, 4), 512, 0, stream>>>(Ab, enc, amask, Pb);
  ctxB_k<<<dim3(Bb, 8), 256, 0, stream>>>(Pb, enc, ctxb);
  ctxC_k<<<dim3(Hh, 8), 256, 0, stream>>>(ctxb, v_ca, arenaB);
  // o_ca projection consumes ctxC's 8 partials directly in staging
  proj_k<1,8><<<dim3(16, 16), 256, 0, stream>>>(arenaB, 131072, o_ca, nullptr, nullptr,
                                                arenaA, Ee, Ee);
  // fused: reduce + LN + residual, dual-output (ds3, out_dec) + chained LN -> zb
  ln_k<false,true,true,true,16,true><<<Bb, 512, 0, stream>>>(
      (const float4*)arenaA, nullptr, 32768, 0, ln_ca_s, ln_ca_b,
      (const float4*)ds2, (float4*)ds3, (float4*)out_dec, glu_ln0_b, (float4*)zb);

  // --- GLU block ---
  proj_k<2,1><<<dim3(32, 16), 256, 0, stream>>>(zb, 0, fc0, fc1, nullptr, arenaA, Ee, Gg);
  // fused: reduce(16 partials of w0,v1) + GELU-GLU + LN
  ln_k<true,true,false,false,16,false><<<Bb, 1024, 0, stream>>>(
      (const float4*)arenaA, nullptr, 131072, 65536, glu_ln1_s, glu_ln1_b,
      nullptr, (float4*)wvn, nullptr, nullptr, nullptr);
  proj_k<1,1><<<dim3(16, 32), 256, 0, stream>>>(wvn, 0, fc2, nullptr, nullptr, arenaB, Gg, Ee);
  reduce_k<true><<<128, 256, 0, stream>>>((const float4*)arenaB, (float4*)out_dec, 32, 32768);
}

// Round 5
// 1082.004 us; speedup vs baseline: 1.2676x; 1.0245x over previous
//
#include <hip/hip_runtime.h>

// Sizes fixed by the problem
#define Bb   64
#define Ee   2048
#define Tt   64
#define Gg   4096
#define Ii   256
#define Hh   32
#define Dd   64

using f32x4_t  = __attribute__((ext_vector_type(4))) float;

__device__ __forceinline__ float gelu_f(float x) {
  return 0.5f * x * (1.0f + erff(x * 0.70710678118654752f));
}

// ---------------- state copy fused with KV-cache update at token_index ----------------
__global__ void copy_state_k(const float4* __restrict__ src, float4* __restrict__ dst,
                             const float4* __restrict__ kb, const float4* __restrict__ vb,
                             const int* __restrict__ tokp) {
  const int t = *tokp;
  const long n4 = (long)128 * Ii * (Ee / 4);
  long i = (long)blockIdx.x * blockDim.x + threadIdx.x;
  const long stride = (long)gridDim.x * blockDim.x;
  for (; i < n4; i += stride) {
    long row = i >> 9;                 // / (Ee/4)
    int tt = (int)(row & (Ii - 1));
    float4 v;
    if (tt == t) {                     // wave-uniform (rows are 512 float4 wide)
      int bh  = (int)(row >> 8);       // 0..127
      int col = (int)(i & 511);
      const float4* s = (bh < Bb) ? kb : vb;
      v = s[(long)(bh & (Bb - 1)) * (Ee / 4) + col];
    } else {
      v = src[i];
    }
    dst[i] = v;
  }
}

// ---------------- layer norm, fused split-K reduce + optional chained 2nd LN ----------------
// KB==0: read in1[base]. KB>0: row value = sum_k in1[k*kstr4 + base] (partial arena).
// GELU+KB>0: second operand = sum_k in1[k*kstr4 + off2 + base].
// SECOND: also emit out3 = LN(out1_row, scale=None, bias2) -- stats are block-local.
template <bool GELU, bool HAS_SCALE, bool HAS_RES, bool DUAL, int KB, bool SECOND>
__global__ void ln_k(const float4* __restrict__ in1, const float4* __restrict__ in2,
                     long kstr4, long off2,
                     const float* __restrict__ scale, const float* __restrict__ bias,
                     const float4* __restrict__ res,
                     float4* __restrict__ out1, float4* __restrict__ out2,
                     const float* __restrict__ bias2, float4* __restrict__ out3) {
  const int row = blockIdx.x, tid = threadIdx.x;
  const int C = blockDim.x * 4;
  const long base = (long)row * blockDim.x + tid;

  float4 p;
  if (KB == 0) {
    p = in1[base];
  } else {
    p = make_float4(0.f, 0.f, 0.f, 0.f);
    #pragma unroll
    for (int k = 0; k < KB; k++) {
      float4 q = in1[(long)k * kstr4 + base];
      p.x += q.x; p.y += q.y; p.z += q.z; p.w += q.w;
    }
  }
  if (GELU) {
    float4 vv;
    if (KB == 0) {
      vv = in2[base];
    } else {
      vv = make_float4(0.f, 0.f, 0.f, 0.f);
      #pragma unroll
      for (int k = 0; k < KB; k++) {
        float4 q = in1[(long)k * kstr4 + off2 + base];
        vv.x += q.x; vv.y += q.y; vv.z += q.z; vv.w += q.w;
      }
    }
    p.x = gelu_f(p.x) * vv.x; p.y = gelu_f(p.y) * vv.y;
    p.z = gelu_f(p.z) * vv.z; p.w = gelu_f(p.w) * vv.w;
  }
  float s  = p.x + p.y + p.z + p.w;
  float s2 = p.x * p.x + p.y * p.y + p.z * p.z + p.w * p.w;

  __shared__ float rs[16], rs2[16];
  int lane = tid & 63, w = tid >> 6;
  #pragma unroll
  for (int o = 32; o; o >>= 1) { s += __shfl_down(s, o, 64); s2 += __shfl_down(s2, o, 64); }
  if (lane == 0) { rs[w] = s; rs2[w] = s2; }
  __syncthreads();
  if (tid == 0) {
    float ts = 0.f, ts2 = 0.f;
    int nw = blockDim.x >> 6;
    for (int i = 0; i < nw; i++) { ts += rs[i]; ts2 += rs2[i]; }
    float mu = ts / C;
    float var = ts2 / C - mu * mu;
    rs[0]  = mu;
    rs2[0] = rsqrtf(var + 1e-6f);
  }
  __syncthreads();
  const float mu = rs[0], rstd = rs2[0];

  float4 o;
  o.x = (p.x - mu) * rstd; o.y = (p.y - mu) * rstd;
  o.z = (p.z - mu) * rstd; o.w = (p.w - mu) * rstd;
  if (HAS_SCALE) {
    float4 sc4 = ((const float4*)scale)[tid];
    o.x *= sc4.x; o.y *= sc4.y; o.z *= sc4.z; o.w *= sc4.w;
  }
  float4 b4 = ((const float4*)bias)[tid];
  o.x += b4.x; o.y += b4.y; o.z += b4.z; o.w += b4.w;
  if (HAS_RES) {
    float4 r4 = res[base];
    o.x += r4.x; o.y += r4.y; o.z += r4.z; o.w += r4.w;
  }
  out1[base] = o;
  if (DUAL) out2[base] = o;

  if (SECOND) {
    // chained LN of the row just produced (scale=None, bias=bias2)
    float t1 = o.x + o.y + o.z + o.w;
    float t2 = o.x * o.x + o.y * o.y + o.z * o.z + o.w * o.w;
    #pragma unroll
    for (int q = 32; q; q >>= 1) { t1 += __shfl_down(t1, q, 64); t2 += __shfl_down(t2, q, 64); }
    __syncthreads();                       // protect rs reuse (phase-1 reads done)
    if (lane == 0) { rs[w] = t1; rs2[w] = t2; }
    __syncthreads();
    if (tid == 0) {
      float ts = 0.f, ts2 = 0.f;
      int nw = blockDim.x >> 6;
      for (int i = 0; i < nw; i++) { ts += rs[i]; ts2 += rs2[i]; }
      float mu2 = ts / C;
      float var2 = ts2 / C - mu2 * mu2;
      rs[0]  = mu2;
      rs2[0] = rsqrtf(var2 + 1e-6f);
    }
    __syncthreads();
    const float mu2 = rs[0], rstd2 = rs2[0];
    float4 bb = ((const float4*)bias2)[tid];
    float4 o2;
    o2.x = (o.x - mu2) * rstd2 + bb.x; o2.y = (o.y - mu2) * rstd2 + bb.y;
    o2.z = (o.z - mu2) * rstd2 + bb.z; o2.w = (o.w - mu2) * rstd2 + bb.w;
    out3[base] = o2;
  }
}

// ---------------- M=64 projection, atomic-free split-K ----------------
// block 256 = 32 n-quads x 8 m-groups(8 rows); grid (N/128, K/kchunk).
// (round-3 lesson: 512-thr/4-row variant doubles the weight VMEM issue count
// per FLOP -> ~2x slower; rows/thread must stay high. round-5 fix: occupancy
// for the latency-exposed NW=1 kernels comes from MORE BLOCKS via kchunk=64,
// not more threads -- same issue count, 2 blocks/CU instead of 1.)
// XP>1: X is a partial arena (stride xstr floats), staging sums XP partials
// on the fly (L2-resident).
template <int NW, int XP>
__global__ __launch_bounds__(256)
void proj_k(const float* __restrict__ X, long xstr,
            const float* __restrict__ W0, const float* __restrict__ W1,
            const float* __restrict__ W2,
            float* __restrict__ P, int K, int N, int kchunk) {
  __shared__ float Xs[64 * 64];
  const int nq = threadIdx.x & 31;
  const int m0 = (threadIdx.x >> 5) * 8;
  const int n  = blockIdx.x * 128 + nq * 4;
  const int kbase = blockIdx.y * kchunk;

  f32x4_t acc[NW][8];
  #pragma unroll
  for (int wsel = 0; wsel < NW; wsel++)
    #pragma unroll
    for (int i = 0; i < 8; i++) acc[wsel][i] = (f32x4_t){0.f, 0.f, 0.f, 0.f};

  for (int k0 = kbase; k0 < kbase + kchunk; k0 += 64) {
    __syncthreads();
    #pragma unroll
    for (int j = 0; j < 16; j++) {
      int e = threadIdx.x + j * 256;        // e = m*64 + kk  (coalesced global read)
      long off = (long)(e >> 6) * K + k0 + (e & 63);
      float sx = X[off];
      if (XP > 1) {
        #pragma unroll
        for (int k = 1; k < XP; k++) sx += X[(long)k * xstr + off];
      }
      Xs[e] = sx;
    }
    __syncthreads();
    #pragma unroll 4
    for (int kk = 0; kk < 64; kk++) {
      const long wrow = (long)(k0 + kk) * N + n;
      f32x4_t w4[NW];
      w4[0] = *(const f32x4_t*)(W0 + wrow);
      if (NW > 1) w4[1] = *(const f32x4_t*)(W1 + wrow);
      if (NW > 2) w4[2] = *(const f32x4_t*)(W2 + wrow);
      #pragma unroll
      for (int i = 0; i < 8; i++) {
        float xm = Xs[(m0 + i) * 64 + kk];   // 2-way LDS broadcast (free)
        #pragma unroll
        for (int wsel = 0; wsel < NW; wsel++) acc[wsel][i] += xm * w4[wsel];
      }
    }
  }
  float* base = P + (long)blockIdx.y * ((long)NW * 64 * N);
  #pragma unroll
  for (int wsel = 0; wsel < NW; wsel++) {
    #pragma unroll
    for (int i = 0; i < 8; i++) {
      *(f32x4_t*)(base + ((long)wsel * 64 + m0 + i) * N + n) = acc[wsel][i];
    }
  }
}

// ---------------- split-K reduce: Y[e] (+)= sum_k P[k*n4 + e] ----------------
template <bool ACCUM>
__global__ void reduce_k(const float4* __restrict__ P, float4* __restrict__ Y,
                         int KB, long n4) {
  long i = (long)blockIdx.x * blockDim.x + threadIdx.x;
  if (i >= n4) return;
  float4 s = ACCUM ? Y[i] : make_float4(0.f, 0.f, 0.f, 0.f);
  for (int k = 0; k < KB; k++) {
    float4 p = P[(long)k * n4 + i];
    s.x += p.x; s.y += p.y; s.z += p.z; s.w += p.w;
  }
  Y[i] = s;
}

// ---------------- self-attention (Q=1, fp32 cache): one wave per (b,h) ----------------
__global__ void attn_k(const float* __restrict__ Q, const float* __restrict__ Kc,
                       const float* __restrict__ Vc, float* __restrict__ O,
                       const int* __restrict__ tokp, int L, long bstride, float scale) {
  const int b = blockIdx.x, h = blockIdx.y;
  const int lane = threadIdx.x;                 // 64 threads = 1 wave
  __shared__ float sc[256];
  const float* qp = Q + (long)b * Ee + h * Dd;  // wave-uniform -> scalar loads
  const int n = *tokp + 1;

  float mx = -3.0e38f;
  for (int pos = lane; pos < n; pos += 64) {
    const float* kr = Kc + (long)b * bstride + (long)pos * Ee + h * Dd;
    float acc = 0.f;
    #pragma unroll
    for (int j = 0; j < 16; j++) {
      float4 kv = *(const float4*)(kr + j * 4);
      acc += qp[j*4+0]*kv.x + qp[j*4+1]*kv.y + qp[j*4+2]*kv.z + qp[j*4+3]*kv.w;
    }
    float s = acc * scale;
    sc[pos] = s;
    mx = fmaxf(mx, s);
  }
  __syncthreads();
  #pragma unroll
  for (int o = 32; o; o >>= 1) mx = fmaxf(mx, __shfl_down(mx, o, 64));
  mx = __shfl(mx, 0, 64);

  float sum = 0.f;
  for (int pos = lane; pos < n; pos += 64) {
    float e = expf(sc[pos] - mx);
    sc[pos] = e;
    sum += e;
  }
  __syncthreads();
  #pragma unroll
  for (int o = 32; o; o >>= 1) sum += __shfl_down(sum, o, 64);
  sum = __shfl(sum, 0, 64);
  const float inv = 1.0f / sum;

  const float* vbase = Vc + (long)b * bstride + h * Dd + lane;
  float acc = 0.f;
  int pos = 0;
  for (; pos + 8 <= n; pos += 8) {
    #pragma unroll
    for (int u = 0; u < 8; u++)
      acc += sc[pos + u] * vbase[(long)(pos + u) * Ee];
  }
  for (; pos < n; pos++) acc += sc[pos] * vbase[(long)pos * Ee];
  O[(long)b * Ee + h * Dd + lane] = acc * inv;
}

// =====================================================================================
// Cross-attention, rank-1-per-batch restructure (Q=1 decode):
//   scores[b,h,t] = (q_h . k_ca[:,h]^T) . enc[b,t,:]   -> never materialize ek (34 GF)
//   out[b,h,:]    = (P[b,h,:] @ enc_b) @ v_ca[:,h]     -> never materialize ev (34 GF)
// =====================================================================================

// A[b,h,e] = 0.125 * sum_c q2[b, h*64+c] * k_ca[e, h*64+c]
// grid (H=32, E/128=16), 256 threads. Per-head 64x128x64 GEMM.
__global__ __launch_bounds__(256)
void headA_k(const float* __restrict__ Q, const float* __restrict__ Kca,
             float* __restrict__ A) {
  const int h  = blockIdx.x;
  const int e0 = blockIdx.y * 128;
  __shared__ float Qs[64][64];     // [b][c]
  __shared__ float Kt[64][132];    // [c][e], +4 pad keeps 16B alignment + spreads banks
  const int tid = threadIdx.x;

  #pragma unroll
  for (int j = 0; j < 16; j++) {
    int idx = tid + j * 256;                       // 4096 elems
    Qs[idx >> 6][idx & 63] = Q[(long)(idx >> 6) * Ee + h * 64 + (idx & 63)];
  }
  #pragma unroll
  for (int j = 0; j < 32; j++) {
    int idx = tid + j * 256;                       // 8192 elems
    int r = idx >> 6, c = idx & 63;                // coalesced global read
    Kt[c][r] = Kca[(long)(e0 + r) * Ee + h * 64 + c];
  }
  __syncthreads();

  const int nq = tid & 31, m0 = (tid >> 5) * 8;
  f32x4_t acc[8];
  #pragma unroll
  for (int i = 0; i < 8; i++) acc[i] = (f32x4_t){0.f, 0.f, 0.f, 0.f};
  #pragma unroll 8
  for (int c = 0; c < 64; c++) {
    f32x4_t w4 = *(const f32x4_t*)&Kt[c][nq * 4];  // contiguous 512B/half-wave: no conflict
    #pragma unroll
    for (int i = 0; i < 8; i++) acc[i] += Qs[m0 + i][c] * w4;
  }
  #pragma unroll
  for (int i = 0; i < 8; i++)
    *(f32x4_t*)&A[((long)(m0 + i) * Hh + h) * Ee + e0 + nq * 4] = acc[i] * 0.125f;
}

// scores + softmax: P[b,h,t] = softmax_t( sum_e A[b,h,e]*enc[b,t,e] + maskbias )
// grid (B=64, 4 head-groups of 8), 512 threads: wave w owns head hg*8+w, lane = t.
// (round-3 lesson: 2 head-groups = 128 blocks leaves half the CUs idle -> 4 groups.)
__global__ __launch_bounds__(512)
void sm_k(const float* __restrict__ A, const float* __restrict__ enc,
          const int* __restrict__ mask, float* __restrict__ P) {
  const int b = blockIdx.x, hg = blockIdx.y;
  __shared__ float Es[64][65];     // [t][e-chunk], +1 pad -> 2-way on read (free)
  __shared__ float As[8][64];
  const int tid = threadIdx.x;
  const int t = tid & 63, h2 = tid >> 6;   // h2 = wave index = head within group

  float s = 0.f;
  for (int e0 = 0; e0 < Ee; e0 += 64) {
    __syncthreads();
    #pragma unroll
    for (int j = 0; j < 8; j++) {
      int idx = tid + j * 512;
      Es[idx >> 6][idx & 63] = enc[((long)b * Tt + (idx >> 6)) * Ee + e0 + (idx & 63)];
    }
    As[h2][t] = A[((long)b * Hh + hg * 8 + h2) * Ee + e0 + t];  // 1 row/wave, coalesced
    __syncthreads();
    #pragma unroll 8
    for (int e = 0; e < 64; e++) s += As[h2][e] * Es[t][e];     // As wave-uniform bcast
  }

  if (mask[(long)b * Tt + t] == 0) s = -1e30f;
  float mv = s;
  #pragma unroll
  for (int o = 32; o; o >>= 1) mv = fmaxf(mv, __shfl_xor(mv, o, 64));
  float p = expf(s - mv);
  float d = p;
  #pragma unroll
  for (int o = 32; o; o >>= 1) d += __shfl_xor(d, o, 64);
  P[((long)b * Hh + hg * 8 + h2) * Tt + t] = p / d;
}

// ctx[b,h,e] = sum_t P[b,h,t] * enc[b,t,e]
// grid (B=64, E/256=8), 256 threads: thread owns column e0+tid for all 32 heads.
__global__ __launch_bounds__(256)
void ctxB_k(const float* __restrict__ P, const float* __restrict__ enc,
            float* __restrict__ C) {
  const int b = blockIdx.x, e0 = blockIdx.y * 256;
  __shared__ float Ps[32][64];
  const int tid = threadIdx.x;
  #pragma unroll
  for (int j = 0; j < 8; j++) {
    int idx = tid + j * 256;
    Ps[idx >> 6][idx & 63] = P[(long)b * (Hh * Tt) + idx];
  }
  __syncthreads();

  float acc[32];
  #pragma unroll
  for (int h = 0; h < 32; h++) acc[h] = 0.f;
  const float* ep = enc + (long)b * Tt * Ee + e0 + tid;
  for (int t0 = 0; t0 < Tt; t0 += 4) {
    float ev0 = ep[(long)(t0 + 0) * Ee];
    float ev1 = ep[(long)(t0 + 1) * Ee];
    float ev2 = ep[(long)(t0 + 2) * Ee];
    float ev3 = ep[(long)(t0 + 3) * Ee];
    #pragma unroll
    for (int h = 0; h < 32; h++) {
      f32x4_t p4 = *(const f32x4_t*)&Ps[h][t0];    // wave-uniform b128 broadcast
      acc[h] += p4[0] * ev0 + p4[1] * ev1 + p4[2] * ev2 + p4[3] * ev3;
    }
  }
  #pragma unroll
  for (int h = 0; h < 32; h++)
    C[((long)b * Hh + h) * Ee + e0 + tid] = acc[h];
}

// cb-partials[kb][b, h*64+c] = sum_{e in chunk} ctx[b,h,e] * v_ca[e, h*64+c]
// grid (H=32, 8 k-chunks of 256), 256 threads = 16 n-quads x 16 m-groups(4 rows).
__global__ __launch_bounds__(256)
void ctxC_k(const float* __restrict__ C, const float* __restrict__ Vca,
            float* __restrict__ Pout) {
  const int h  = blockIdx.x;
  const int kb = blockIdx.y;
  __shared__ float Xs[64][65];     // [b][kk], pad kills 16-way on scalar read
  __shared__ float Ws[64][64];     // [kk][c]
  const int tid = threadIdx.x;
  const int nq = tid & 15, m0 = (tid >> 4) * 4;

  f32x4_t acc[4];
  #pragma unroll
  for (int i = 0; i < 4; i++) acc[i] = (f32x4_t){0.f, 0.f, 0.f, 0.f};

  for (int k0 = kb * 256; k0 < kb * 256 + 256; k0 += 64) {
    __syncthreads();
    #pragma unroll
    for (int j = 0; j < 16; j++) {
      int idx = tid + j * 256;
      int r = idx >> 6, cc = idx & 63;
      Xs[r][cc] = C[((long)r * Hh + h) * Ee + k0 + cc];
      Ws[r][cc] = Vca[(long)(k0 + r) * Ee + h * 64 + cc];
    }
    __syncthreads();
    #pragma unroll 4
    for (int kk = 0; kk < 64; kk++) {
      f32x4_t w4 = *(const f32x4_t*)&Ws[kk][nq * 4];
      #pragma unroll
      for (int i = 0; i < 4; i++) acc[i] += Xs[m0 + i][kk] * w4;
    }
  }
  #pragma unroll
  for (int i = 0; i < 4; i++)
    *(f32x4_t*)&Pout[((long)kb * 64 + m0 + i) * Ee + h * 64 + nq * 4] = acc[i];
}

extern "C" void kernel_launch(void* const* d_in, const int* in_sizes, int n_in,
                              void* d_out, int out_size, void* d_ws, size_t ws_size,
                              hipStream_t stream) {
  const float* dec    = (const float*)d_in[0];
  const float* enc    = (const float*)d_in[1];
  const float* astate = (const float*)d_in[2];
  const int*   amask  = (const int*)d_in[3];
  const int*   tokp   = (const int*)d_in[4];
  const float* ln_pre_sa_b = (const float*)d_in[5];
  const float* q_sa = (const float*)d_in[6];
  const float* k_sa = (const float*)d_in[7];
  const float* v_sa = (const float*)d_in[8];
  const float* o_sa = (const float*)d_in[9];
  const float* ln_sa_s = (const float*)d_in[10];
  const float* ln_sa_b = (const float*)d_in[11];
  const float* ln_pre_ca_b = (const float*)d_in[12];
  const float* q_ca = (const float*)d_in[13];
  const float* k_ca = (const float*)d_in[14];
  const float* v_ca = (const float*)d_in[15];
  const float* o_ca = (const float*)d_in[16];
  const float* ln_ca_s = (const float*)d_in[17];
  const float* ln_ca_b = (const float*)d_in[18];
  const float* glu_ln0_b = (const float*)d_in[19];
  const float* fc0 = (const float*)d_in[20];
  const float* fc1 = (const float*)d_in[21];
  const float* glu_ln1_s = (const float*)d_in[22];
  const float* glu_ln1_b = (const float*)d_in[23];
  const float* fc2 = (const float*)d_in[24];

  float* out_dec   = (float*)d_out;
  float* out_state = out_dec + (long)Bb * Ee;

  // ---- workspace carve (floats) ----
  float* qb  = (float*)d_ws;            // qb,kb,vb contiguous (one reduce)
  float* kb  = qb  + 131072;
  float* vb  = kb  + 131072;
  float* q2  = vb  + 131072;
  float* x1  = q2  + 131072;
  float* ab  = x1  + 131072;
  float* ds2 = ab  + 131072;
  float* x3  = ds2 + 131072;
  float* ds3 = x3  + 131072;
  float* zb  = ds3 + 131072;
  float* wvn = zb  + 131072;            // 64*4096
  float* Ab   = wvn + 262144;           // A[b][h][e]   64*32*2048
  float* ctxb = Ab  + 4194304;          // ctx[b][h][e] 64*32*2048
  float* Pb   = ctxb + 4194304;         // P[b][h][t]   64*32*64
  float* arenaA = Pb + 131072;          // split-K partials (max 16x2x64x4096 = 33.5MB)
  float* arenaB = arenaA + 8388608;     // second arena (ctxC partials / fc2 partials)

  // --- self-attention block ---
  ln_k<false,false,false,false,0,false><<<Bb, 512, 0, stream>>>(
      (const float4*)dec, nullptr, 0, 0, nullptr, ln_pre_sa_b, nullptr,
      (float4*)x1, nullptr, nullptr, nullptr);
  proj_k<3,1><<<dim3(16, 16), 256, 0, stream>>>(x1, 0, q_sa, k_sa, v_sa,
                                                arenaA, Ee, Ee, 128);
  reduce_k<false><<<384, 256, 0, stream>>>((const float4*)arenaA, (float4*)qb, 16, 98304);
  copy_state_k<<<4096, 256, 0, stream>>>((const float4*)astate, (float4*)out_state,
                                         (const float4*)kb, (const float4*)vb, tokp);
  attn_k<<<dim3(Bb, Hh), 64, 0, stream>>>(qb, out_state,
      out_state + (long)Bb * Ii * Ee, ab, tokp, Ii, (long)Ii * Ee, 0.125f);
  // o_sa proj: kchunk=64 -> 512 blocks = 2 blocks/CU (latency hiding for NW=1)
  proj_k<1,1><<<dim3(16, 32), 256, 0, stream>>>(ab, 0, o_sa, nullptr, nullptr,
                                                arenaA, Ee, Ee, 64);
  // fused: reduce(32 partials) + LN + residual + chained LN -> ds2 AND x3
  ln_k<false,true,true,false,32,true><<<Bb, 512, 0, stream>>>(
      (const float4*)arenaA, nullptr, 32768, 0, ln_sa_s, ln_sa_b,
      (const float4*)dec, (float4*)ds2, nullptr, ln_pre_ca_b, (float4*)x3);

  // --- cross-attention block (rank-1 restructure: no ek/ev materialization) ---
  proj_k<1,1><<<dim3(16, 32), 256, 0, stream>>>(x3, 0, q_ca, nullptr, nullptr,
                                                arenaA, Ee, Ee, 64);
  reduce_k<false><<<128, 256, 0, stream>>>((const float4*)arenaA, (float4*)q2, 32, 32768);
  headA_k<<<dim3(Hh, 16), 256, 0, stream>>>(q2, k_ca, Ab);
  sm_k<<<dim3(Bb, 4), 512, 0, stream>>>(Ab, enc, amask, Pb);
  ctxB_k<<<dim3(Bb, 8), 256, 0, stream>>>(Pb, enc, ctxb);
  ctxC_k<<<dim3(Hh, 8), 256, 0, stream>>>(ctxb, v_ca, arenaB);
  // o_ca projection consumes ctxC's 8 partials directly in staging; kchunk=64
  proj_k<1,8><<<dim3(16, 32), 256, 0, stream>>>(arenaB, 131072, o_ca, nullptr, nullptr,
                                                arenaA, Ee, Ee, 64);
  // fused: reduce(32) + LN + residual, dual-output (ds3, out_dec) + chained LN -> zb
  ln_k<false,true,true,true,32,true><<<Bb, 512, 0, stream>>>(
      (const float4*)arenaA, nullptr, 32768, 0, ln_ca_s, ln_ca_b,
      (const float4*)ds2, (float4*)ds3, (float4*)out_dec, glu_ln0_b, (float4*)zb);

  // --- GLU block ---
  proj_k<2,1><<<dim3(32, 16), 256, 0, stream>>>(zb, 0, fc0, fc1, nullptr,
                                                arenaA, Ee, Gg, 128);
  // fused: reduce(16 partials of w0,v1) + GELU-GLU + LN
  ln_k<true,true,false,false,16,false><<<Bb, 1024, 0, stream>>>(
      (const float4*)arenaA, nullptr, 131072, 65536, glu_ln1_s, glu_ln1_b,
      nullptr, (float4*)wvn, nullptr, nullptr, nullptr);
  proj_k<1,1><<<dim3(16, 32), 256, 0, stream>>>(wvn, 0, fc2, nullptr, nullptr,
                                                arenaB, Gg, Ee, 128);
  reduce_k<true><<<128, 256, 0, stream>>>((const float4*)arenaB, (float4*)out_dec, 32, 32768);
}